// Round 1
// baseline (38.161 us; speedup 1.0000x reference)
//
#include <hip/hip_runtime.h>

// Problem constants (from reference)
#define BB 256
#define GG 16
#define LL 16
#define CC 8192
#define KK 8
// GAMMA_NEG=4, GAMMA_POS=1, CLIP=0.05, EPS=1e-8

__device__ __forceinline__ float sigmoid_fast(float x) {
    float e = __expf(-x);                       // v_exp_f32 path
    return __builtin_amdgcn_rcpf(1.0f + e);     // v_rcp_f32 (~1 ulp)
}

// loss element for target == 0
__device__ __forceinline__ float f_neg(float x) {
    float s  = sigmoid_fast(x);
    float xn = fminf(1.05f - s, 1.0f);          // min(1 - s + CLIP, 1)
    float l  = __logf(fmaxf(xn, 1e-8f));
    float t  = 1.0f - xn;                       // pt = xn, gamma = 4
    float t2 = t * t;
    return -l * (t2 * t2);
}

// loss element for target == 1
__device__ __forceinline__ float f_pos(float x) {
    float s = sigmoid_fast(x);
    float l = __logf(fmaxf(s, 1e-8f));
    return -l * (1.0f - s);                     // pt = s, gamma = 1
}

// ---------------------------------------------------------------------------
// Kernel 1: per-(g,b) row sum of f_neg over C. One block per row (G*B rows).
// One coalesced float4 streaming pass over the whole 128 MiB logits tensor.
// ---------------------------------------------------------------------------
__global__ __launch_bounds__(256) void negsum_kernel(
    const float* __restrict__ logits, float* __restrict__ negsum) {
    const int row = blockIdx.x;                          // row = g*B + b
    const float4* rp = reinterpret_cast<const float4*>(logits) + (size_t)row * (CC / 4);
    float acc = 0.0f;
#pragma unroll
    for (int i = 0; i < (CC / 4) / 256; ++i) {           // 8 iters
        float4 v = rp[threadIdx.x + i * 256];
        acc += f_neg(v.x) + f_neg(v.y) + f_neg(v.z) + f_neg(v.w);
    }
#pragma unroll
    for (int off = 32; off > 0; off >>= 1) acc += __shfl_down(acc, off, 64);
    __shared__ float sm[4];
    if ((threadIdx.x & 63) == 0) sm[threadIdx.x >> 6] = acc;
    __syncthreads();
    if (threadIdx.x == 0) negsum[row] = (sm[0] + sm[1]) + (sm[2] + sm[3]);
}

// ---------------------------------------------------------------------------
// Kernel 2: one thread per (b,l). per_node = negsum[p*B+b] + pos-corrections
// for the distinct labeled classes (dup labels clamp to 1 in the reference).
// Block-reduce -> one partial per block.
// ---------------------------------------------------------------------------
__global__ __launch_bounds__(256) void corr_kernel(
    const float* __restrict__ logits, const int* __restrict__ param,
    const int* __restrict__ label, const int* __restrict__ num,
    const float* __restrict__ negsum, float* __restrict__ partial) {
    const int t = blockIdx.x * 256 + threadIdx.x;        // (b,l) flat index
    float per_node = 0.0f;
    if (t < BB * LL) {
        const int b  = t / LL;
        const int pv = param[t];
        if (pv >= 0) {                                   // valid mask
            const int p = min(pv, GG - 1);
            const int n = min(num[t], KK);
            const int* lab = label + (size_t)t * KK;
            const float* rowp = logits + ((size_t)p * BB + b) * (size_t)CC;
            int cs[KK];
#pragma unroll
            for (int k = 0; k < KK; ++k) cs[k] = lab[k];
            float corr = negsum[p * BB + b];
#pragma unroll
            for (int k = 0; k < KK; ++k) {
                if (k < n) {
                    bool dup = false;
#pragma unroll
                    for (int j = 0; j < k; ++j) dup = dup || (cs[j] == cs[k]);
                    if (!dup) {
                        float x = rowp[cs[k]];
                        corr += f_pos(x) - f_neg(x);
                    }
                }
            }
            per_node = corr;
        }
    }
#pragma unroll
    for (int off = 32; off > 0; off >>= 1) per_node += __shfl_down(per_node, off, 64);
    __shared__ float sm[4];
    if ((threadIdx.x & 63) == 0) sm[threadIdx.x >> 6] = per_node;
    __syncthreads();
    if (threadIdx.x == 0) partial[blockIdx.x] = (sm[0] + sm[1]) + (sm[2] + sm[3]);
}

// ---------------------------------------------------------------------------
// Kernel 3: reduce the 16 block partials, divide by B.
// ---------------------------------------------------------------------------
__global__ void final_kernel(const float* __restrict__ partial,
                             float* __restrict__ out, int nPartial) {
    float v = (threadIdx.x < nPartial) ? partial[threadIdx.x] : 0.0f;
#pragma unroll
    for (int off = 32; off > 0; off >>= 1) v += __shfl_down(v, off, 64);
    if (threadIdx.x == 0) out[0] = v * (1.0f / (float)BB);
}

extern "C" void kernel_launch(void* const* d_in, const int* in_sizes, int n_in,
                              void* d_out, int out_size, void* d_ws, size_t ws_size,
                              hipStream_t stream) {
    const float* logits = (const float*)d_in[0];   // (G, B, C) f32
    const int*   param  = (const int*)d_in[1];     // (B, L)
    const int*   label  = (const int*)d_in[2];     // (B, L, K)
    const int*   num    = (const int*)d_in[3];     // (B, L)
    float* out = (float*)d_out;
    float* ws  = (float*)d_ws;
    float* negsum  = ws;                 // G*B = 4096 floats
    float* partial = ws + GG * BB;       // 16 floats

    negsum_kernel<<<GG * BB, 256, 0, stream>>>(logits, negsum);
    const int nb = (BB * LL + 255) / 256;            // 16 blocks
    corr_kernel<<<nb, 256, 0, stream>>>(logits, param, label, num, negsum, partial);
    final_kernel<<<1, 64, 0, stream>>>(partial, out, nb);
}